// Round 3
// baseline (290.992 us; speedup 1.0000x reference)
//
#include <hip/hip_runtime.h>
#include <cstdint>
#include <cstddef>

// ---------------- workspace layout (bytes) ----------------
// Wp   : packed gate-interleaved weight, bf16, 768x1024 (4 cb x 32 kb tiles, 192x32) = 1,572,864
// Fp   : packed fco_w, bf16, 256x256 (2 nb x 8 kb tiles, 128x32)                     =   131,072
// bp   : permuted bias (c = h*3+g), f32, 768
// hvp  : packed hidden vector, bf16, 32768x256 (256 mb x 8 kb tiles, 128x32)
#define WS_WP   0
#define WS_FCO  1572864
#define WS_BP   1703936
#define WS_HVP  1707008

typedef __attribute__((ext_vector_type(8))) __bf16 bf16x8;
typedef __attribute__((ext_vector_type(4))) __bf16 bf16x4;
typedef __attribute__((ext_vector_type(4))) float floatx4;

__device__ __forceinline__ unsigned short f2bf(float f) {
  unsigned int u = __builtin_bit_cast(unsigned int, f);
  u += 0x7fffu + ((u >> 16) & 1u);   // RNE
  return (unsigned short)(u >> 16);
}

__device__ __forceinline__ float sigmf(float z) {
  return __builtin_amdgcn_rcpf(1.f + __expf(-z));
}
__device__ __forceinline__ float tanh_(float z) {
  return 1.f - 2.f * __builtin_amdgcn_rcpf(1.f + __expf(2.f * z));
}

__device__ __forceinline__ void gld16(const void* g, void* l) {
  __builtin_amdgcn_global_load_lds(
      (const __attribute__((address_space(1))) unsigned int*)g,
      (__attribute__((address_space(3))) unsigned int*)l, 16, 0, 0);
}

// ---------------- merged pack kernel (unchanged) ----------------
__global__ __launch_bounds__(256) void pack_k(
    const float* __restrict__ wr, const float* __restrict__ wi,
    const float* __restrict__ wj, const float* __restrict__ wk,
    const float* __restrict__ bx, const float* __restrict__ fw,
    unsigned short* __restrict__ Wp, unsigned short* __restrict__ Fp,
    float* __restrict__ bp) {
  int t = threadIdx.x;
  if (blockIdx.x < 384) {
    int gpp = blockIdx.x >> 7;        // 0..2 -> gates {input,output,cell}
    int oct = blockIdx.x & 127;       // f-octet
    int gp = gpp + 1;                 // skip dead forget gate
    int h = t;                        // 0..255, lane-contiguous
    int hb = h >> 6, hr = h & 63;     // hb wave-uniform
    int f0 = oct << 3;
    int fb = f0 >> 8, fr0 = f0 & 255;
    const int   comp_t[4][4] = {{0,1,2,3},{1,0,3,2},{2,3,0,1},{3,2,1,0}};
    const float sign_t[4][4] = {{1.f,-1.f,-1.f,-1.f},{1.f,1.f,-1.f,1.f},
                                {1.f,1.f,1.f,-1.f},{1.f,-1.f,1.f,1.f}};
    const float* srcs[4] = {wr, wi, wj, wk};
    const float* s = srcs[comp_t[hb][fb]] + ((size_t)((gp << 8) + fr0)) * 64 + hr;
    float sg = sign_t[hb][fb];
    unsigned short v[8];
#pragma unroll
    for (int j = 0; j < 8; ++j) v[j] = f2bf(sg * s[(size_t)j * 64]);
    int c = h * 3 + gpp;
    int cb = c / 192, nl = c % 192;
    int kb = oct >> 2, q = oct & 3;
    int idx16 = (nl << 2) + (q ^ ((nl >> 1) & 3));
    uint4 val = make_uint4(
        (unsigned)v[0] | ((unsigned)v[1] << 16), (unsigned)v[2] | ((unsigned)v[3] << 16),
        (unsigned)v[4] | ((unsigned)v[5] << 16), (unsigned)v[6] | ((unsigned)v[7] << 16));
    *(uint4*)(Wp + (size_t)(cb * 32 + kb) * 6144 + idx16 * 8) = val;
    if (oct == 0) bp[c] = bx[(gp << 8) + h];
  } else {
    int oct = blockIdx.x - 384;       // k-octet 0..31
    int n = t;
    int k0 = oct << 3;
    unsigned short v[8];
#pragma unroll
    for (int j = 0; j < 8; ++j) v[j] = f2bf(fw[(size_t)(k0 + j) * 256 + n]);
    int nb = n >> 7, nl = n & 127, kb = oct >> 2, q = oct & 3;
    int idx16 = (nl << 2) + (q ^ ((nl >> 1) & 3));
    uint4 val = make_uint4(
        (unsigned)v[0] | ((unsigned)v[1] << 16), (unsigned)v[2] | ((unsigned)v[3] << 16),
        (unsigned)v[4] | ((unsigned)v[5] << 16), (unsigned)v[6] | ((unsigned)v[7] << 16));
    *(uint4*)(Fp + (size_t)((nb << 3) + kb) * 4096 + idx16 * 8) = val;
  }
}

// ---------------- GEMM1 + fused LSTM gates ----------------
// THEORY (this revision): R0-R2 all plateau at ~111-114 us with MfmaUtil ~19%
// regardless of LDS traffic or schedule -> per-step accounting (4180 cyc/CU-step
// vs 233 MFMA + ~1100 LDS) points at A-operand SUPPLY: x (134 MB fp32) re-read
// 4x (once per cby) = 536 MB through the L3 path at ~8.3 TB/s request rate.
// Fix: 512-thread, 8-wave block computes a 128x384 tile (TWO cby groups), waves
// 2M x 4N so each wave keeps the identical 64x96 sub-tile / acc[4][6] inner
// loop. x re-read 4x -> 2x (536 -> 268 MB). Per-CU-step LDS, MFMA and barrier
// counts are UNCHANGED -> discriminating experiment for supply-bound theory.
// Schedule: same 3-buffer counted-vmcnt (never 0 in main loop), vmcnt(5)/step.
__global__ __launch_bounds__(512, 2) void gemm1_k(
    const float* __restrict__ x, const unsigned short* __restrict__ Wp,
    const float* __restrict__ bp, unsigned short* __restrict__ hvp) {
  __shared__ char smem[98304];                  // 3 x 32 KB (A bf16 8K + B bf16 24K)
  float* zep = (float*)smem;                    // epilogue: 32 x 385 f32 = 49.3 KB

  const int t = threadIdx.x;
  const int lane = t & 63, wid = t >> 6;
  const int wm = wid >> 2, wn = wid & 3;        // 2M x 4N wave grid
  const int lrow = lane & 15, q = lane >> 4;
  const int rowt = blockIdx.x;                  // 0..255 (fast dim: W stays L2-hot)
  const int nbq = blockIdx.y;                   // 0..1 -> cby pair {2*nbq, 2*nbq+1}
  const int cb0 = nbq * 2;
  const int row0 = rowt * 128;
  const float* xbase = x + (size_t)row0 * 1024;

  // A staging: thread t handles float4 at rows {t>>3, (t>>3)+64}, k-quad t&7.
  // Each 8-lane group covers one 128B row segment (perfect coalescing).
  const int m0 = t >> 3, kq = t & 7;
  const int sq8 = kq >> 1, shalf = kq & 1;

  floatx4 acc[4][6];
#pragma unroll
  for (int i = 0; i < 4; ++i)
#pragma unroll
    for (int j = 0; j < 6; ++j) acc[i][j] = (floatx4){0.f, 0.f, 0.f, 0.f};

  // B: 1536 slots of 16B (2 cbL halves of 768); per-thread 3 gld16.
  // Wave-uniform cbL per (wave, i_) since 768 % 64 == 0.
#define STAGE_B(bufi, kt)                                                     \
  {                                                                           \
    unsigned short* sBs_ = (unsigned short*)(smem + (bufi) * 32768 + 8192);   \
    const unsigned short* bt0_ = Wp + ((size_t)cb0 * 32 + (kt)) * 6144;       \
    _Pragma("unroll")                                                         \
    for (int i_ = 0; i_ < 3; ++i_) {                                          \
      int s_ = t + i_ * 512;                                                  \
      int cbL_ = s_ >= 768;                                                   \
      const unsigned short* src_ =                                            \
          bt0_ + (size_t)cbL_ * 196608 + (s_ - cbL_ * 768) * 8;               \
      gld16(src_, sBs_ + s_ * 8);                                             \
    }                                                                         \
  }
#define LOAD_A(ra, kt)                                                        \
  {                                                                           \
    const float* ab_ = xbase + (size_t)m0 * 1024 + (kt) * 32 + kq * 4;        \
    ra[0] = *(const float4*)(ab_);                                            \
    ra[1] = *(const float4*)(ab_ + 64 * 1024);                                \
  }
#define WRITE_A(ra, bufi)                                                     \
  {                                                                           \
    unsigned short* sAs_ = (unsigned short*)(smem + (bufi) * 32768);          \
    _Pragma("unroll")                                                         \
    for (int i_ = 0; i_ < 2; ++i_) {                                          \
      int m_ = m0 + i_ * 64;                                                  \
      int slot_ = (m_ << 2) + (sq8 ^ ((m_ >> 1) & 3));                        \
      bf16x4 v_;                                                              \
      v_[0] = (__bf16)ra[i_].x; v_[1] = (__bf16)ra[i_].y;                     \
      v_[2] = (__bf16)ra[i_].z; v_[3] = (__bf16)ra[i_].w;                     \
      *(bf16x4*)(sAs_ + slot_ * 8 + shalf * 4) = v_;                          \
    }                                                                         \
  }
#define COMPUTE(bufi)                                                         \
  {                                                                           \
    const unsigned short* sA_ = (const unsigned short*)(smem + (bufi) * 32768);\
    const unsigned short* sB_ = sA_ + 4096;                                   \
    bf16x8 af[4], bf[6];                                                      \
    _Pragma("unroll")                                                         \
    for (int mt = 0; mt < 4; ++mt) {                                          \
      int m = wm * 64 + mt * 16 + lrow;                                       \
      int slot = (m << 2) + (q ^ ((m >> 1) & 3));                             \
      af[mt] = *(const bf16x8*)(const void*)(sA_ + slot * 8);                 \
    }                                                                         \
    _Pragma("unroll")                                                         \
    for (int nt = 0; nt < 6; ++nt) {                                          \
      int nl = (wn & 1) * 96 + nt * 16 + lrow;                                \
      int off16 = (nl << 2) + (q ^ ((nl >> 1) & 3));                          \
      bf[nt] = *(const bf16x8*)(const void*)(                                 \
          sB_ + ((size_t)(wn >> 1) * 768 + off16) * 8);                       \
    }                                                                         \
    _Pragma("unroll")                                                         \
    for (int mt = 0; mt < 4; ++mt)                                            \
      _Pragma("unroll")                                                       \
      for (int nt = 0; nt < 6; ++nt)                                          \
        acc[mt][nt] = __builtin_amdgcn_mfma_f32_16x16x32_bf16(                \
            af[mt], bf[nt], acc[mt][nt], 0, 0, 0);                            \
  }
// BODY: RC holds A(kt+1) (in flight or arrived); RN receives A(kt+2).
// Invariant at top of iter kt: buf[kt%3] staged; 5 vmem in flight for kt+1.
#define BODY(kt, RC, RN)                                                      \
  {                                                                           \
    if ((kt) < 30) {                                                          \
      LOAD_A(RN, (kt) + 2)                                                    \
      STAGE_B(((kt) + 2) % 3, (kt) + 2)                                       \
    }                                                                         \
    COMPUTE((kt) % 3)                                                         \
    if ((kt) < 30) {                                                          \
      asm volatile("s_waitcnt vmcnt(5)" ::: "memory");                        \
    } else {                                                                  \
      asm volatile("s_waitcnt vmcnt(0)" ::: "memory");                        \
    }                                                                         \
    if ((kt) < 31) { WRITE_A(RC, ((kt) + 1) % 3) }                            \
    asm volatile("s_waitcnt lgkmcnt(0)" ::: "memory");                        \
    __builtin_amdgcn_s_barrier();                                             \
    asm volatile("" ::: "memory");                                            \
  }

  float4 raA[2], raB[2];
  // Prologue: raA=A(0), raB=A(1); B(0)->buf0, B(1)->buf1; A(0) written to buf0.
  LOAD_A(raA, 0)
  STAGE_B(0, 0)
  LOAD_A(raB, 1)
  STAGE_B(1, 1)
  WRITE_A(raA, 0)                               // compiler waits raA's vmem
  asm volatile("s_waitcnt vmcnt(5)" ::: "memory");   // B(0) landed; raB+B(1) in flight
  asm volatile("s_waitcnt lgkmcnt(0)" ::: "memory");
  __builtin_amdgcn_s_barrier();
  asm volatile("" ::: "memory");

  for (int kt2 = 0; kt2 < 32; kt2 += 2) {
    BODY(kt2, raB, raA)                         // even kt: consume raB=A(kt+1)
    BODY(kt2 + 1, raA, raB)                     // odd kt: consume raA=A(kt+1)
  }
#undef BODY
#undef COMPUTE
#undef STAGE_B
#undef LOAD_A
#undef WRITE_A
  __syncthreads();                              // all K-loop LDS reads done before zep reuse

  // Epilogue: 4 passes of 32 rows via LDS (pitch 385 f32), fused gates,
  // hv stored in gemm2's packed-swizzled tile layout. 512 threads cover
  // 32 rows x 128 h (2 cbL groups) per pass.
  const float* bp0 = bp + cb0 * 192;
  const int er = t >> 4, oc = t & 15;           // row 0..31, h-octet 0..15
  const int cbL = oc >> 3, oo = oc & 7;
#pragma unroll
  for (int pass = 0; pass < 4; ++pass) {
    if (wm == (pass >> 1)) {
      int mtb = (pass & 1) * 2;
#pragma unroll
      for (int mi = 0; mi < 2; ++mi)
#pragma unroll
        for (int nt = 0; nt < 6; ++nt)
#pragma unroll
          for (int r = 0; r < 4; ++r)
            zep[(mi * 16 + q * 4 + r) * 385 + wn * 96 + nt * 16 + lrow] = acc[mtb + mi][nt][r];
    }
    __syncthreads();
    {
      int ml = pass * 32 + er;                  // local row 0..127
      unsigned short v[8];
#pragma unroll
      for (int j = 0; j < 8; ++j) {
        int hl = oo * 8 + j;                    // 0..63 local h within cbL group
        int cz = cbL * 192 + hl * 3;
        float zi = zep[er * 385 + cz + 0] + bp0[cz + 0];
        float zo = zep[er * 385 + cz + 1] + bp0[cz + 1];
        float zc = zep[er * 385 + cz + 2] + bp0[cz + 2];
        float it = sigmf(zi);
        float ot = sigmf(zo);
        float cc = it * tanh_(zc);
        v[j] = f2bf(ot * tanh_(cc));
      }
      int ktile = (cb0 + cbL) * 2 + (oo >> 2), qq = oo & 3;
      int idx16 = (ml << 2) + (qq ^ ((ml >> 1) & 3));
      uint4 val = make_uint4(
          (unsigned)v[0] | ((unsigned)v[1] << 16), (unsigned)v[2] | ((unsigned)v[3] << 16),
          (unsigned)v[4] | ((unsigned)v[5] << 16), (unsigned)v[6] | ((unsigned)v[7] << 16));
      *(uint4*)(hvp + (size_t)(rowt * 8 + ktile) * 4096 + idx16 * 8) = val;
    }
    __syncthreads();
  }
}

// ---------------- GEMM2: out = hv @ fco_w + fco_b (fp32 output, unchanged) ----------------
__global__ __launch_bounds__(256, 4) void gemm2_k(
    const unsigned short* __restrict__ hvp, const unsigned short* __restrict__ Fp,
    const float* __restrict__ fcob, float* __restrict__ out) {
  __shared__ unsigned short sB[32768];          // 64 KB: 8 k-tiles of 128x32
  const int t = threadIdx.x;
  const int lane = t & 63, wid = t >> 6;
  const int wm = wid >> 1, wn = wid & 1;
  const int lrow = lane & 15, q = lane >> 4;
  const int mb = blockIdx.x, nb = blockIdx.y;

  const unsigned short* fpb = Fp + (size_t)nb * 32768;
#pragma unroll
  for (int i = 0; i < 16; ++i) gld16(fpb + (t + i * 256) * 8, sB + (t + i * 256) * 8);

  floatx4 acc[4][4];
#pragma unroll
  for (int i = 0; i < 4; ++i)
#pragma unroll
    for (int j = 0; j < 4; ++j) acc[i][j] = (floatx4){0.f, 0.f, 0.f, 0.f};
  __syncthreads();

#pragma unroll
  for (int kt = 0; kt < 8; ++kt) {
    const unsigned short* at_ = hvp + (size_t)(mb * 8 + kt) * 4096;
    bf16x8 af[4], bf[4];
#pragma unroll
    for (int mt = 0; mt < 4; ++mt) {
      int m = wm * 64 + mt * 16 + lrow;
      int o = (m << 2) + (q ^ ((m >> 1) & 3));
      af[mt] = *(const bf16x8*)(const void*)(at_ + o * 8);    // global, coalesced
    }
#pragma unroll
    for (int nt = 0; nt < 4; ++nt) {
      int n = wn * 64 + nt * 16 + lrow;
      int o = (n << 2) + (q ^ ((n >> 1) & 3));
      bf[nt] = *(const bf16x8*)(const void*)(sB + kt * 4096 + o * 8);
    }
#pragma unroll
    for (int mt = 0; mt < 4; ++mt)
#pragma unroll
      for (int nt = 0; nt < 4; ++nt)
        acc[mt][nt] = __builtin_amdgcn_mfma_f32_16x16x32_bf16(af[mt], bf[nt], acc[mt][nt], 0, 0, 0);
  }
#pragma unroll
  for (int nt = 0; nt < 4; ++nt) {
    int colg = nb * 128 + wn * 64 + nt * 16 + lrow;
    float bias = fcob[colg];
#pragma unroll
    for (int mt = 0; mt < 4; ++mt) {
      int rowg = mb * 128 + wm * 64 + mt * 16 + q * 4;
#pragma unroll
      for (int r = 0; r < 4; ++r)
        out[(size_t)(rowg + r) * 256 + colg] = acc[mt][nt][r] + bias;
    }
  }
}

extern "C" void kernel_launch(void* const* d_in, const int* in_sizes, int n_in,
                              void* d_out, int out_size, void* d_ws, size_t ws_size,
                              hipStream_t stream) {
  const float* x  = (const float*)d_in[0];
  const float* wr = (const float*)d_in[1];
  const float* wi = (const float*)d_in[2];
  const float* wj = (const float*)d_in[3];
  const float* wk = (const float*)d_in[4];
  const float* bx = (const float*)d_in[5];
  // d_in[6..9] = uh_* are dead (h0 == 0)
  const float* fw = (const float*)d_in[10];
  const float* fb = (const float*)d_in[11];
  char* ws = (char*)d_ws;
  unsigned short* Wp  = (unsigned short*)(ws + WS_WP);
  unsigned short* Fp  = (unsigned short*)(ws + WS_FCO);
  float*          bp  = (float*)(ws + WS_BP);
  unsigned short* hvp = (unsigned short*)(ws + WS_HVP);
  float*          out = (float*)d_out;

  hipLaunchKernelGGL(pack_k,  dim3(416),    dim3(256), 0, stream, wr, wi, wj, wk, bx, fw, Wp, Fp, bp);
  hipLaunchKernelGGL(gemm1_k, dim3(256, 2), dim3(512), 0, stream, x, Wp, bp, hvp);
  hipLaunchKernelGGL(gemm2_k, dim3(256, 2), dim3(256), 0, stream, hvp, Fp, fb, out);
}